// Round 2
// baseline (671.034 us; speedup 1.0000x reference)
//
#include <hip/hip_runtime.h>

#define BATCH 16
#define SEQ   4096
#define HEADS 16
#define EMB   64
#define SS    64      // s = sqrt(SEQ)
#define NW    127     // 2*s - 1
#define PLANE (HEADS * EMB)            // 1024 floats per seq position

// workspace arrays, all [b][x][h][e] = 16*64*16*64 floats = 4 MB each
#define SUMS_ELEMS (BATCH * SS * PLANE)

// ---------------------------------------------------------------------------
// Kernel 1: one fully-coalesced float4 pass over v, producing
//   u_s[b][i][h][e] = sum_j v[b][i*64+j][h][e]   (complete per block, plain write)
//   v_s[b][j][h][e] = sum_i v[b][i*64+j][h][e]   (16-way chunk partials, atomic merge)
// Grid: B*16 = 256 blocks (b, ic); block covers i in [ic*4, ic*4+4), ALL heads.
// 1024 threads: g = tid>>8 owns j-range [g*16, g*16+16), t = tid&255 is the
// float4 column (h,e) index. Every wave load = 64 lanes x 16B = 1KB contiguous.
// ---------------------------------------------------------------------------
__global__ __launch_bounds__(1024) void sums_kernel(
    const float4* __restrict__ v4, float* __restrict__ vs,
    float4* __restrict__ us4)
{
    __shared__ float4 upart[4][4][256];   // [g][il][t] : 64 KB

    const int blk = blockIdx.x;           // b*16 + ic
    const int b   = blk >> 4;
    const int ic  = blk & 15;
    const int tid = threadIdx.x;
    const int g   = tid >> 8;             // 0..3 : j-quarter
    const int t   = tid & 255;            // float4 column within (h,e) plane

    const float4* base = v4 + ((size_t)(b * SEQ + ic * 256) << 8) + t;

    float4 uacc[4], vacc[16];
    #pragma unroll
    for (int il = 0; il < 4; ++il) uacc[il] = make_float4(0.f, 0.f, 0.f, 0.f);
    #pragma unroll
    for (int jj = 0; jj < 16; ++jj) vacc[jj] = make_float4(0.f, 0.f, 0.f, 0.f);

    #pragma unroll
    for (int il = 0; il < 4; ++il) {
        const float4* p = base + ((size_t)(il * 64 + g * 16) << 8);
        #pragma unroll
        for (int jj = 0; jj < 16; ++jj) {
            const float4 x = p[(size_t)jj << 8];
            uacc[il].x += x.x; uacc[il].y += x.y; uacc[il].z += x.z; uacc[il].w += x.w;
            vacc[jj].x += x.x; vacc[jj].y += x.y; vacc[jj].z += x.z; vacc[jj].w += x.w;
        }
    }

    // ---- u_s: merge the 4 j-quarters via LDS, write complete rows ----
    #pragma unroll
    for (int il = 0; il < 4; ++il) upart[g][il][t] = uacc[il];
    __syncthreads();
    {
        const int il2 = tid >> 8;
        float4 s = upart[0][il2][t];
        #pragma unroll
        for (int gg = 1; gg < 4; ++gg) {
            const float4 q = upart[gg][il2][t];
            s.x += q.x; s.y += q.y; s.z += q.z; s.w += q.w;
        }
        us4[((size_t)(b * SS + ic * 4 + il2) << 8) + t] = s;
    }

    // ---- v_s: merge chunk partials across the 16 ic-blocks via atomics ----
    float* vsp = vs + ((size_t)(b * SS + g * 16) << 10) + (t << 2);
    #pragma unroll
    for (int jj = 0; jj < 16; ++jj) {
        float* p = vsp + ((size_t)jj << 10);
        atomicAdd(p + 0, vacc[jj].x);
        atomicAdd(p + 1, vacc[jj].y);
        atomicAdd(p + 2, vacc[jj].z);
        atomicAdd(p + 3, vacc[jj].w);
    }
}

// ---------------------------------------------------------------------------
// Kernel 2: 64x64 circular-Toeplitz matvec per (b,h) for BOTH v_s -> RxV and
// u_s -> RxU, sharing one 31-entry register window of w per 16x16 tile.
// RxV[b][t][h][e] = sum_j w[h][(t-j+64)%127] * v_s[b][j][h][e]; same for U.
// Grid: B*H = 256 blocks, 256 threads (4 waves x 16 t-values), lane = e.
// ---------------------------------------------------------------------------
__global__ __launch_bounds__(256) void conv_kernel(
    const float* __restrict__ w, const float* __restrict__ vs,
    const float* __restrict__ us, float* __restrict__ rxv,
    float* __restrict__ rxu)
{
    __shared__ float wtab[NW];
    __shared__ float vsl[SS][SS];
    __shared__ float usl[SS][SS];

    const int bh   = blockIdx.x;
    const int b    = bh >> 4;
    const int h    = bh & (HEADS - 1);
    const int tid  = threadIdx.x;
    const int wave = tid >> 6;
    const int lane = tid & 63;

    if (tid < NW) wtab[tid] = w[h * NW + tid];
    for (int idx = tid; idx < SS * SS; idx += 256) {
        const int j = idx >> 6, e = idx & 63;
        const size_t gofs = ((size_t)(b * SS + j) << 10) + (h << 6) + e;
        vsl[j][e] = vs[gofs];
        usl[j][e] = us[gofs];
    }
    __syncthreads();

    const int t0 = wave * 16;
    float accv[16], accu[16];
    #pragma unroll
    for (int tt = 0; tt < 16; ++tt) { accv[tt] = 0.0f; accu[tt] = 0.0f; }

    #pragma unroll
    for (int jb = 0; jb < 4; ++jb) {
        float wreg[31];
        #pragma unroll
        for (int d = 0; d < 31; ++d) {
            int idx = t0 - jb * 16 + 49 + d;   // in [1,127]
            if (idx >= NW) idx -= NW;
            wreg[d] = wtab[idx];
        }
        #pragma unroll
        for (int jj = 0; jj < 16; ++jj) {
            const float cv = vsl[jb * 16 + jj][lane];
            const float cu = usl[jb * 16 + jj][lane];
            #pragma unroll
            for (int tt = 0; tt < 16; ++tt) {
                const float cw = wreg[15 + tt - jj];   // = w[(t-j+64)%127]
                accv[tt] += cw * cv;
                accu[tt] += cw * cu;
            }
        }
    }

    #pragma unroll
    for (int tt = 0; tt < 16; ++tt) {
        const size_t o = ((size_t)(b * SS + t0 + tt) << 10) + (h << 6) + lane;
        rxv[o] = accv[tt];
        rxu[o] = accu[tt];
    }
}

// ---------------------------------------------------------------------------
// Kernel 3: expand. out[b, i*64+j, h, e] = RxV[b][j][h][e] + RxU[b][i][h][e].
// Grid: B*64 = 1024 blocks (one per (b,i)), 256 threads, float4 everywhere.
// ---------------------------------------------------------------------------
__global__ __launch_bounds__(256) void expand_kernel(
    const float* __restrict__ rxv, const float* __restrict__ rxu,
    float* __restrict__ out)
{
    const int blk = blockIdx.x;        // b*64 + i
    const int b   = blk >> 6;
    const int tid = threadIdx.x;

    const float4 ru = *((const float4*)(rxu + ((size_t)blk << 10)) + tid);
    const float4* rvb = (const float4*)(rxv + ((size_t)b << 16));
    float4* ob = (float4*)(out + (((size_t)blk) << 16)) + tid;

    #pragma unroll 8
    for (int j = 0; j < SS; ++j) {
        float4 rv = rvb[(j << 8) + tid];
        float4 r;
        r.x = rv.x + ru.x; r.y = rv.y + ru.y;
        r.z = rv.z + ru.z; r.w = rv.w + ru.w;
        ob[(size_t)j << 8] = r;
    }
}

// ---------------------------------------------------------------------------
// z_pb: zp[h][t] = s * sum_j o_[j] * w[h, (t-j+64)%127]
// out2[0, i*64+j, h] = zp[h][j] + zp[h][i].  Grid: 64 blocks (one per i).
// ---------------------------------------------------------------------------
__global__ __launch_bounds__(256) void zpb_kernel(const float* __restrict__ w,
                                                  const float* __restrict__ o_,
                                                  float* __restrict__ out2) {
    __shared__ float zp[HEADS][SS];
    __shared__ float osh[SS];
    __shared__ float wsh[HEADS * NW];

    const int tid = threadIdx.x;
    const int g   = blockIdx.x;   // i index

    if (tid < SS) osh[tid] = o_[tid];
    for (int idx = tid; idx < HEADS * NW; idx += 256) wsh[idx] = w[idx];
    __syncthreads();

    for (int idx = tid; idx < HEADS * SS; idx += 256) {
        const int h = idx / SS, t = idx % SS;
        float acc = 0.0f;
        #pragma unroll
        for (int j = 0; j < SS; ++j) {
            int k = t - j + 64;
            if (k >= NW) k -= NW;
            acc += osh[j] * wsh[h * NW + k];
        }
        zp[h][t] = acc * (float)SS;
    }
    __syncthreads();

    for (int idx = tid; idx < SS * HEADS; idx += 256) {
        const int tl = idx / HEADS, h = idx % HEADS;
        out2[(size_t)(g * SS + tl) * HEADS + h] = zp[h][tl] + zp[h][g];
    }
}

extern "C" void kernel_launch(void* const* d_in, const int* in_sizes, int n_in,
                              void* d_out, int out_size, void* d_ws, size_t ws_size,
                              hipStream_t stream) {
    const float* v  = (const float*)d_in[0];
    const float* w  = (const float*)d_in[1];
    const float* o_ = (const float*)d_in[2];
    float* out = (float*)d_out;

    float* vs  = (float*)d_ws;                 // 4 MB, atomically accumulated
    float* us  = vs  + SUMS_ELEMS;             // 4 MB
    float* rxv = us  + SUMS_ELEMS;             // 4 MB
    float* rxu = rxv + SUMS_ELEMS;             // 4 MB

    // zero only the atomic target
    hipMemsetAsync(vs, 0, (size_t)SUMS_ELEMS * sizeof(float), stream);

    sums_kernel<<<BATCH * 16, 1024, 0, stream>>>((const float4*)v, vs, (float4*)us);
    conv_kernel<<<BATCH * HEADS, 256, 0, stream>>>(w, vs, us, rxv, rxu);
    expand_kernel<<<BATCH * SS, 256, 0, stream>>>(rxv, rxu, out);

    const size_t out1_elems = (size_t)BATCH * SEQ * HEADS * EMB;
    zpb_kernel<<<SS, 256, 0, stream>>>(w, o_, out + out1_elems);
}

// Round 3
// 499.150 us; speedup vs baseline: 1.3444x; 1.3444x over previous
//
#include <hip/hip_runtime.h>

#define BATCH 16
#define SEQ   4096
#define HEADS 16
#define EMB   64
#define SS    64      // s = sqrt(SEQ)
#define NW    127     // 2*s - 1
#define PLANE (HEADS * EMB)            // 1024 floats per seq position

#define SUMS_ELEMS (BATCH * SS * PLANE)            // 1M floats = 4 MB
#define VPART_ELEMS (BATCH * 16 * SS * PLANE)      // 16M floats = 64 MB
// ws layout: v_part (64MB) | us (4MB) | rxv (4MB) | rxu (4MB)
#define WS_NEEDED ((size_t)(VPART_ELEMS + 3 * SUMS_ELEMS) * sizeof(float))

// ---------------------------------------------------------------------------
// Kernel 1: one coalesced float4 pass over v. NO atomics.
//   u_s[b][i][cols]           : complete per block (LDS merge), plain store
//   v_part[b][ic][j][cols]    : per-chunk partial (sum over 4 i's), plain store
// Grid: 512 = ((b*16 + ic) << 1) | ch.  Block covers i in [ic*4,ic*4+4),
// all 64 j, col-half ch (128 float4 of the 256-float4 (h,e) plane).
// 512 threads: t = tid&127 (float4 col in half), g = tid>>7 (j-quarter).
// ---------------------------------------------------------------------------
__global__ __launch_bounds__(512) void sums_kernel(
    const float4* __restrict__ v4, float4* __restrict__ vpart4,
    float4* __restrict__ us4)
{
    __shared__ float4 upart[4][4][128];   // [g][il][t] : 32 KB

    const int blk = blockIdx.x;
    const int ch  = blk & 1;
    const int bic = blk >> 1;             // b*16 + ic
    const int ic  = bic & 15;
    const int b   = bic >> 4;
    const int tid = threadIdx.x;
    const int g   = tid >> 7;             // 0..3 : j-quarter
    const int t   = tid & 127;            // float4 col within half
    const int col4 = ch * 128 + t;

    const float4* base = v4 + ((size_t)(b * SEQ + ic * 256) << 8) + col4;

    float4 uacc[4], vacc[16];
    #pragma unroll
    for (int il = 0; il < 4; ++il) uacc[il] = make_float4(0.f, 0.f, 0.f, 0.f);
    #pragma unroll
    for (int jj = 0; jj < 16; ++jj) vacc[jj] = make_float4(0.f, 0.f, 0.f, 0.f);

    #pragma unroll
    for (int il = 0; il < 4; ++il) {
        const float4* p = base + ((size_t)(il * 64 + g * 16) << 8);
        #pragma unroll
        for (int jj = 0; jj < 16; ++jj) {
            const float4 x = p[(size_t)jj << 8];
            uacc[il].x += x.x; uacc[il].y += x.y; uacc[il].z += x.z; uacc[il].w += x.w;
            vacc[jj].x += x.x; vacc[jj].y += x.y; vacc[jj].z += x.z; vacc[jj].w += x.w;
        }
    }

    // ---- u_s: merge 4 j-quarters in LDS, write complete rows ----
    #pragma unroll
    for (int il = 0; il < 4; ++il) upart[g][il][t] = uacc[il];
    __syncthreads();
    {
        const int il2 = tid >> 7;         // 0..3
        const int t2  = tid & 127;
        float4 s = upart[0][il2][t2];
        #pragma unroll
        for (int gg = 1; gg < 4; ++gg) {
            const float4 q = upart[gg][il2][t2];
            s.x += q.x; s.y += q.y; s.z += q.z; s.w += q.w;
        }
        us4[((size_t)(b * SS + ic * 4 + il2) << 8) + ch * 128 + t2] = s;
    }

    // ---- v_s partial: disjoint plain stores, merged later in conv ----
    #pragma unroll
    for (int jj = 0; jj < 16; ++jj) {
        vpart4[((size_t)(bic * SS + g * 16 + jj) << 8) + col4] = vacc[jj];
    }
}

// ---------------------------------------------------------------------------
// Kernel 2: merge 16 v_s partials + circular-Toeplitz matvec for RxV and RxU.
// RxV[b][t][h][e] = sum_j w[h][(t-j+64)%127] * v_s[b][j][h][e]; same for U.
// Grid: B*H = 256 blocks, 256 threads (4 waves x 16 t-values), lane = e.
// ---------------------------------------------------------------------------
__global__ __launch_bounds__(256) void conv_kernel(
    const float* __restrict__ w, const float4* __restrict__ vpart4,
    const float4* __restrict__ us4, float* __restrict__ rxv,
    float* __restrict__ rxu)
{
    __shared__ float wtab[NW];
    __shared__ float vsl[SS][SS];
    __shared__ float usl[SS][SS];

    const int bh   = blockIdx.x;
    const int b    = bh >> 4;
    const int h    = bh & (HEADS - 1);
    const int tid  = threadIdx.x;
    const int wave = tid >> 6;
    const int lane = tid & 63;

    if (tid < NW) wtab[tid] = w[h * NW + tid];

    // merge the 16 ic-partials of v_s for this (b,h) slice
    for (int slot = tid; slot < SS * 16; slot += 256) {   // slot = j*16 + e4
        const int j = slot >> 4, e4 = slot & 15;
        float4 acc = make_float4(0.f, 0.f, 0.f, 0.f);
        #pragma unroll
        for (int ic = 0; ic < 16; ++ic) {
            const float4 x = vpart4[((size_t)((b * 16 + ic) * SS + j) << 8) + (h << 4) + e4];
            acc.x += x.x; acc.y += x.y; acc.z += x.z; acc.w += x.w;
        }
        *(float4*)&vsl[j][e4 * 4] = acc;
        *(float4*)&usl[j][e4 * 4] = us4[((size_t)(b * SS + j) << 8) + (h << 4) + e4];
    }
    __syncthreads();

    const int t0 = wave * 16;
    float accv[16], accu[16];
    #pragma unroll
    for (int tt = 0; tt < 16; ++tt) { accv[tt] = 0.0f; accu[tt] = 0.0f; }

    #pragma unroll
    for (int jb = 0; jb < 4; ++jb) {
        float wreg[31];
        #pragma unroll
        for (int d = 0; d < 31; ++d) {
            int idx = t0 - jb * 16 + 49 + d;   // in [1,127]
            if (idx >= NW) idx -= NW;
            wreg[d] = wtab[idx];
        }
        #pragma unroll
        for (int jj = 0; jj < 16; ++jj) {
            const float cv = vsl[jb * 16 + jj][lane];
            const float cu = usl[jb * 16 + jj][lane];
            #pragma unroll
            for (int tt = 0; tt < 16; ++tt) {
                const float cw = wreg[15 + tt - jj];   // = w[(t-j+64)%127]
                accv[tt] += cw * cv;
                accu[tt] += cw * cu;
            }
        }
    }

    #pragma unroll
    for (int tt = 0; tt < 16; ++tt) {
        const size_t o = ((size_t)(b * SS + t0 + tt) << 10) + (h << 6) + lane;
        rxv[o] = accv[tt];
        rxu[o] = accu[tt];
    }
}

// ---------------------------------------------------------------------------
// Kernel 3: expand. out[b, i*64+j, h, e] = RxV[b][j][h][e] + RxU[b][i][h][e].
// Grid: B*64 = 1024 blocks (one per (b,i)), 256 threads, float4 everywhere.
// ---------------------------------------------------------------------------
__global__ __launch_bounds__(256) void expand_kernel(
    const float* __restrict__ rxv, const float* __restrict__ rxu,
    float* __restrict__ out)
{
    const int blk = blockIdx.x;        // b*64 + i
    const int b   = blk >> 6;
    const int tid = threadIdx.x;

    const float4 ru = *((const float4*)(rxu + ((size_t)blk << 10)) + tid);
    const float4* rvb = (const float4*)(rxv + ((size_t)b << 16));
    float4* ob = (float4*)(out + (((size_t)blk) << 16)) + tid;

    #pragma unroll 8
    for (int j = 0; j < SS; ++j) {
        float4 rv = rvb[(j << 8) + tid];
        float4 r;
        r.x = rv.x + ru.x; r.y = rv.y + ru.y;
        r.z = rv.z + ru.z; r.w = rv.w + ru.w;
        ob[(size_t)j << 8] = r;
    }
}

// ---------------------------------------------------------------------------
// Fallback (ws too small): round-0 fused kernel, verified at 180 us.
// ---------------------------------------------------------------------------
__global__ __launch_bounds__(512) void pbv_kernel(const float* __restrict__ v,
                                                  const float* __restrict__ w,
                                                  float* __restrict__ out) {
    __shared__ float us [SS][SS];
    __shared__ float vsf[SS][SS];
    __shared__ float wtab[NW];

    const int bh   = blockIdx.x;
    const int b    = bh / HEADS;
    const int h    = bh % HEADS;
    const int tid  = threadIdx.x;
    const int wave = tid >> 6;
    const int lane = tid & 63;

    for (int idx = tid; idx < SS * SS; idx += 512) (&vsf[0][0])[idx] = 0.0f;
    if (tid < NW) wtab[tid] = w[h * NW + tid];
    __syncthreads();

    const float* vbase = v + ((size_t)b * SEQ * HEADS + h) * EMB + lane;
    float vsacc[SS];
    #pragma unroll
    for (int j = 0; j < SS; ++j) vsacc[j] = 0.0f;

    for (int ii = 0; ii < 8; ++ii) {
        const int i = wave * 8 + ii;
        const float* rowp = vbase + (size_t)i * SS * (HEADS * EMB);
        float uacc = 0.0f;
        #pragma unroll
        for (int j = 0; j < SS; ++j) {
            float val = rowp[(size_t)j * (HEADS * EMB)];
            uacc += val;
            vsacc[j] += val;
        }
        us[i][lane] = uacc;
    }
    #pragma unroll
    for (int j = 0; j < SS; ++j) atomicAdd(&vsf[j][lane], vsacc[j]);
    __syncthreads();

    float rv[8], ru[8];
    for (int tt = 0; tt < 8; ++tt) {
        const int t = wave * 8 + tt;
        float accv = 0.0f, accu = 0.0f;
        #pragma unroll
        for (int j = 0; j < SS; ++j) {
            int k = t - j + 64;
            if (k >= NW) k -= NW;
            const float c = wtab[k];
            accv += c * vsf[j][lane];
            accu += c * us [j][lane];
        }
        rv[tt] = accv;
        ru[tt] = accu;
    }
    __syncthreads();
    for (int tt = 0; tt < 8; ++tt) {
        const int t = wave * 8 + tt;
        vsf[t][lane] = rv[tt];
        us [t][lane] = ru[tt];
    }
    __syncthreads();

    float* obase = out + ((size_t)b * SEQ * HEADS + h) * EMB + lane;
    for (int ii = 0; ii < 8; ++ii) {
        const int i = wave * 8 + ii;
        const float ruv = us[i][lane];
        #pragma unroll
        for (int j = 0; j < SS; ++j) {
            obase[(size_t)(i * SS + j) * (HEADS * EMB)] = vsf[j][lane] + ruv;
        }
    }
}

// ---------------------------------------------------------------------------
// z_pb: zp[h][t] = s * sum_j o_[j] * w[h, (t-j+64)%127]
// out2[0, i*64+j, h] = zp[h][j] + zp[h][i].  Grid: 64 blocks (one per i).
// ---------------------------------------------------------------------------
__global__ __launch_bounds__(256) void zpb_kernel(const float* __restrict__ w,
                                                  const float* __restrict__ o_,
                                                  float* __restrict__ out2) {
    __shared__ float zp[HEADS][SS];
    __shared__ float osh[SS];
    __shared__ float wsh[HEADS * NW];

    const int tid = threadIdx.x;
    const int g   = blockIdx.x;   // i index

    if (tid < SS) osh[tid] = o_[tid];
    for (int idx = tid; idx < HEADS * NW; idx += 256) wsh[idx] = w[idx];
    __syncthreads();

    for (int idx = tid; idx < HEADS * SS; idx += 256) {
        const int h = idx / SS, t = idx % SS;
        float acc = 0.0f;
        #pragma unroll
        for (int j = 0; j < SS; ++j) {
            int k = t - j + 64;
            if (k >= NW) k -= NW;
            acc += osh[j] * wsh[h * NW + k];
        }
        zp[h][t] = acc * (float)SS;
    }
    __syncthreads();

    for (int idx = tid; idx < SS * HEADS; idx += 256) {
        const int tl = idx / HEADS, h = idx % HEADS;
        out2[(size_t)(g * SS + tl) * HEADS + h] = zp[h][tl] + zp[h][g];
    }
}

extern "C" void kernel_launch(void* const* d_in, const int* in_sizes, int n_in,
                              void* d_out, int out_size, void* d_ws, size_t ws_size,
                              hipStream_t stream) {
    const float* v  = (const float*)d_in[0];
    const float* w  = (const float*)d_in[1];
    const float* o_ = (const float*)d_in[2];
    float* out = (float*)d_out;

    if (ws_size >= WS_NEEDED) {
        float* vpart = (float*)d_ws;                 // 64 MB, disjoint writes
        float* us    = vpart + VPART_ELEMS;          // 4 MB
        float* rxv   = us    + SUMS_ELEMS;           // 4 MB
        float* rxu   = rxv   + SUMS_ELEMS;           // 4 MB

        sums_kernel<<<BATCH * 16 * 2, 512, 0, stream>>>(
            (const float4*)v, (float4*)vpart, (float4*)us);
        conv_kernel<<<BATCH * HEADS, 256, 0, stream>>>(
            w, (const float4*)vpart, (const float4*)us, rxv, rxu);
        expand_kernel<<<BATCH * SS, 256, 0, stream>>>(rxv, rxu, out);
    } else {
        pbv_kernel<<<BATCH * HEADS, 512, 0, stream>>>(v, w, out);
    }

    const size_t out1_elems = (size_t)BATCH * SEQ * HEADS * EMB;
    zpb_kernel<<<SS, 256, 0, stream>>>(w, o_, out + out1_elems);
}

// Round 4
// 461.387 us; speedup vs baseline: 1.4544x; 1.0818x over previous
//
#include <hip/hip_runtime.h>

#define BATCH 16
#define SEQ   4096
#define HEADS 16
#define EMB   64
#define SS    64      // s = sqrt(SEQ)
#define NW    127     // 2*s - 1
#define PLANE (HEADS * EMB)                 // 1024 floats per seq position

#define US_ELEMS    (BATCH * SS * PLANE)    // 1M floats  = 4 MB
#define VPART_ELEMS (BATCH * 4 * SS * PLANE)// 4M floats  = 16 MB
// ws layout: v_part (16MB) | u_s (4MB)
#define WS_NEEDED ((size_t)(VPART_ELEMS + US_ELEMS) * sizeof(float))

// ---------------------------------------------------------------------------
// Kernel 1: fully-contiguous float4 pass over v. No atomics, no memset.
// Grid: 256 = b(16) x q(seq-quarter,4) x cq(col-quarter,4). Block reads
// v[b, q*1024:(q+1)*1024, cols cq*256:+256] -- every wave load is 64 lanes
// x 16B = 1KB contiguous.
// Thread (w=tid>>6, c4=tid&63) covers rows r with r%4==w, float4-col c4.
//   u_s[b][q*16+il][cols]: complete (one LDS merge across the 4 waves).
//   v_part[b][q][j][cols]: per-quarter partial; j==w (mod 4) makes each
//   wave's 16 vacc registers a COMPLETE disjoint slice -> plain stores.
// ---------------------------------------------------------------------------
__global__ __launch_bounds__(256) void sums_kernel(
    const float4* __restrict__ v4, float4* __restrict__ vpart4,
    float4* __restrict__ us4)
{
    __shared__ float4 u_lds[4][16][64];   // [w][il][c4] : 16 KB

    const int blk = blockIdx.x;
    const int b   = blk >> 4;
    const int q   = (blk >> 2) & 3;
    const int cq  = blk & 3;
    const int tid = threadIdx.x;
    const int w   = tid >> 6;             // wave 0..3  == j mod 4
    const int c4  = tid & 63;             // float4 col within quarter

    const float4* base = v4 + (((size_t)(b * SEQ + q * 1024)) << 8)
                            + (cq << 6) + c4;

    float4 vacc[16];
    #pragma unroll
    for (int m = 0; m < 16; ++m) vacc[m] = make_float4(0.f, 0.f, 0.f, 0.f);

    for (int il = 0; il < 16; ++il) {     // local i within quarter
        float4 uacc = make_float4(0.f, 0.f, 0.f, 0.f);
        #pragma unroll
        for (int m = 0; m < 16; ++m) {    // j = w + 4m  (static vacc index!)
            const float4 x = base[(size_t)((il << 6) + w + (m << 2)) << 8];
            uacc.x += x.x; uacc.y += x.y; uacc.z += x.z; uacc.w += x.w;
            vacc[m].x += x.x; vacc[m].y += x.y;
            vacc[m].z += x.z; vacc[m].w += x.w;
        }
        u_lds[w][il][c4] = uacc;
    }
    __syncthreads();

    // u_s: reduce the 4 wave-partials, store complete rows
    {
        int s = tid;
        #pragma unroll
        for (int r = 0; r < 4; ++r, s += 256) {   // 1024 slots / 256 threads
            const int il = s >> 6, c = s & 63;
            float4 a = u_lds[0][il][c];
            #pragma unroll
            for (int ww = 1; ww < 4; ++ww) {
                const float4 x = u_lds[ww][il][c];
                a.x += x.x; a.y += x.y; a.z += x.z; a.w += x.w;
            }
            us4[((size_t)((b << 6) + (q << 4) + il) << 8) + (cq << 6) + c] = a;
        }
    }

    // v_part: disjoint plain stores (wave w owns j = w+4m)
    #pragma unroll
    for (int m = 0; m < 16; ++m) {
        const int j = w + (m << 2);
        vpart4[((size_t)((((b << 2) + q) << 6) + j) << 8) + (cq << 6) + c4]
            = vacc[m];
    }
}

// ---------------------------------------------------------------------------
// Kernel 2: fused merge + circular-Toeplitz conv + expand. Per (b,h).
//   v_s[j][e] = sum_q v_part[b][q][j][h,e];  u_s from ws.
//   RxV[t][e] = sum_j w[h][(t-j+64)%127] * v_s[j][e]; same for RxU.
//   out[b, i*64+j, h, e] = RxV[j][e] + RxU[i][e]   (round-0-verified pattern)
// Grid: 256 blocks, 512 threads (8 waves x 8 t-values), lane = e.
// ---------------------------------------------------------------------------
__global__ __launch_bounds__(512) void convexp_kernel(
    const float* __restrict__ w, const float4* __restrict__ vpart4,
    const float4* __restrict__ us4, float* __restrict__ out)
{
    __shared__ float wtab[NW];
    __shared__ float vsl[SS][SS];   // v_s, later RxV
    __shared__ float usl[SS][SS];   // u_s, later RxU

    const int bh   = blockIdx.x;
    const int b    = bh >> 4;
    const int h    = bh & (HEADS - 1);
    const int tid  = threadIdx.x;
    const int wave = tid >> 6;      // 0..7
    const int lane = tid & 63;      // e

    if (tid < NW) wtab[tid] = w[h * NW + tid];

    for (int s = tid; s < SS * 16; s += 512) {    // s = j*16 + e4
        const int j = s >> 4, e4 = s & 15;
        float4 acc = make_float4(0.f, 0.f, 0.f, 0.f);
        #pragma unroll
        for (int q = 0; q < 4; ++q) {
            const float4 x =
                vpart4[((size_t)((((b << 2) + q) << 6) + j) << 8) + (h << 4) + e4];
            acc.x += x.x; acc.y += x.y; acc.z += x.z; acc.w += x.w;
        }
        *(float4*)&vsl[j][e4 << 2] = acc;
        *(float4*)&usl[j][e4 << 2] =
            us4[((size_t)((b << 6) + j) << 8) + (h << 4) + e4];
    }
    __syncthreads();

    // conv: wave owns t in [wave*8, wave*8+8); shared 23-entry w-window per
    // 16-wide j-block covers all (tt,jj) pairs.
    const int t0 = wave << 3;
    float accv[8], accu[8];
    #pragma unroll
    for (int tt = 0; tt < 8; ++tt) { accv[tt] = 0.0f; accu[tt] = 0.0f; }

    #pragma unroll
    for (int jb = 0; jb < 4; ++jb) {
        float wreg[23];
        #pragma unroll
        for (int d = 0; d < 23; ++d) {
            int idx = t0 - (jb << 4) + 49 + d;   // in [1,127]
            if (idx >= NW) idx -= NW;
            wreg[d] = wtab[idx];
        }
        #pragma unroll
        for (int jj = 0; jj < 16; ++jj) {
            const float cv = vsl[(jb << 4) + jj][lane];
            const float cu = usl[(jb << 4) + jj][lane];
            #pragma unroll
            for (int tt = 0; tt < 8; ++tt) {
                const float cw = wreg[15 + tt - jj];  // = w[(t-j+64)%127]
                accv[tt] += cw * cv;
                accu[tt] += cw * cu;
            }
        }
    }
    __syncthreads();   // all conv reads done before overwrite
    #pragma unroll
    for (int tt = 0; tt < 8; ++tt) {
        vsl[t0 + tt][lane] = accv[tt];   // RxV
        usl[t0 + tt][lane] = accu[tt];   // RxU
    }
    __syncthreads();

    // expand (identical to the verified round-0 phase 3)
    float* obase = out + (((size_t)b * SEQ) << 10) + (h << 6) + lane;
    for (int ii = 0; ii < 8; ++ii) {
        const int i = (wave << 3) + ii;
        const float ruv = usl[i][lane];
        #pragma unroll
        for (int j = 0; j < SS; ++j) {
            obase[(size_t)((i << 6) + j) << 10] = vsl[j][lane] + ruv;
        }
    }
}

// ---------------------------------------------------------------------------
// Fallback (ws too small): round-0 fused kernel, verified at ~180 us.
// ---------------------------------------------------------------------------
__global__ __launch_bounds__(512) void pbv_kernel(const float* __restrict__ v,
                                                  const float* __restrict__ w,
                                                  float* __restrict__ out) {
    __shared__ float us [SS][SS];
    __shared__ float vsf[SS][SS];
    __shared__ float wtab[NW];

    const int bh   = blockIdx.x;
    const int b    = bh / HEADS;
    const int h    = bh % HEADS;
    const int tid  = threadIdx.x;
    const int wave = tid >> 6;
    const int lane = tid & 63;

    for (int idx = tid; idx < SS * SS; idx += 512) (&vsf[0][0])[idx] = 0.0f;
    if (tid < NW) wtab[tid] = w[h * NW + tid];
    __syncthreads();

    const float* vbase = v + ((size_t)b * SEQ * HEADS + h) * EMB + lane;
    float vsacc[SS];
    #pragma unroll
    for (int j = 0; j < SS; ++j) vsacc[j] = 0.0f;

    for (int ii = 0; ii < 8; ++ii) {
        const int i = wave * 8 + ii;
        const float* rowp = vbase + (size_t)i * SS * (HEADS * EMB);
        float uacc = 0.0f;
        #pragma unroll
        for (int j = 0; j < SS; ++j) {
            float val = rowp[(size_t)j * (HEADS * EMB)];
            uacc += val;
            vsacc[j] += val;
        }
        us[i][lane] = uacc;
    }
    #pragma unroll
    for (int j = 0; j < SS; ++j) atomicAdd(&vsf[j][lane], vsacc[j]);
    __syncthreads();

    float rv[8], ru[8];
    for (int tt = 0; tt < 8; ++tt) {
        const int t = wave * 8 + tt;
        float accv = 0.0f, accu = 0.0f;
        #pragma unroll
        for (int j = 0; j < SS; ++j) {
            int k = t - j + 64;
            if (k >= NW) k -= NW;
            const float c = wtab[k];
            accv += c * vsf[j][lane];
            accu += c * us [j][lane];
        }
        rv[tt] = accv;
        ru[tt] = accu;
    }
    __syncthreads();
    for (int tt = 0; tt < 8; ++tt) {
        const int t = wave * 8 + tt;
        vsf[t][lane] = rv[tt];
        us [t][lane] = ru[tt];
    }
    __syncthreads();

    float* obase = out + ((size_t)b * SEQ * HEADS + h) * EMB + lane;
    for (int ii = 0; ii < 8; ++ii) {
        const int i = wave * 8 + ii;
        const float ruv = us[i][lane];
        #pragma unroll
        for (int j = 0; j < SS; ++j) {
            obase[(size_t)(i * SS + j) * (HEADS * EMB)] = vsf[j][lane] + ruv;
        }
    }
}

// ---------------------------------------------------------------------------
// z_pb: zp[h][t] = s * sum_j o_[j] * w[h, (t-j+64)%127]
// out2[0, i*64+j, h] = zp[h][j] + zp[h][i].  Grid: 64 blocks (one per i).
// ---------------------------------------------------------------------------
__global__ __launch_bounds__(256) void zpb_kernel(const float* __restrict__ w,
                                                  const float* __restrict__ o_,
                                                  float* __restrict__ out2) {
    __shared__ float zp[HEADS][SS];
    __shared__ float osh[SS];
    __shared__ float wsh[HEADS * NW];

    const int tid = threadIdx.x;
    const int g   = blockIdx.x;   // i index

    if (tid < SS) osh[tid] = o_[tid];
    for (int idx = tid; idx < HEADS * NW; idx += 256) wsh[idx] = w[idx];
    __syncthreads();

    for (int idx = tid; idx < HEADS * SS; idx += 256) {
        const int h = idx / SS, t = idx % SS;
        float acc = 0.0f;
        #pragma unroll
        for (int j = 0; j < SS; ++j) {
            int k = t - j + 64;
            if (k >= NW) k -= NW;
            acc += osh[j] * wsh[h * NW + k];
        }
        zp[h][t] = acc * (float)SS;
    }
    __syncthreads();

    for (int idx = tid; idx < SS * HEADS; idx += 256) {
        const int tl = idx / HEADS, h = idx % HEADS;
        out2[(size_t)(g * SS + tl) * HEADS + h] = zp[h][tl] + zp[h][g];
    }
}

extern "C" void kernel_launch(void* const* d_in, const int* in_sizes, int n_in,
                              void* d_out, int out_size, void* d_ws, size_t ws_size,
                              hipStream_t stream) {
    const float* v  = (const float*)d_in[0];
    const float* w  = (const float*)d_in[1];
    const float* o_ = (const float*)d_in[2];
    float* out = (float*)d_out;

    if (ws_size >= WS_NEEDED) {
        float* vpart = (float*)d_ws;                 // 16 MB, disjoint writes
        float* us    = vpart + VPART_ELEMS;          // 4 MB

        sums_kernel<<<256, 256, 0, stream>>>(
            (const float4*)v, (float4*)vpart, (float4*)us);
        convexp_kernel<<<BATCH * HEADS, 512, 0, stream>>>(
            w, (const float4*)vpart, (const float4*)us, out);
    } else {
        pbv_kernel<<<BATCH * HEADS, 512, 0, stream>>>(v, w, out);
    }

    const size_t out1_elems = (size_t)BATCH * SEQ * HEADS * EMB;
    zpb_kernel<<<SS, 256, 0, stream>>>(w, o_, out + out1_elems);
}